// Round 2
// baseline (10596.871 us; speedup 1.0000x reference)
//
#include <hip/hip_runtime.h>
#include <hip/hip_bf16.h>
#include <math.h>

#define NROWS 131072

// ---------------------------------------------------------------------------
// Prep: Mf[l] = out_w[l] @ wv[l]   (512x512); wv = attn_in_w[l] rows 1024..1535
// softmax over a size-1 axis == 1, so mha(x_q,x_kv) = x_kv @ (out_w@wv)^T + beff
// ---------------------------------------------------------------------------
__global__ void fuse_w_kernel(const float* __restrict__ in_w,   // (2,1536,512)
                              const float* __restrict__ out_w,  // (2,512,512)
                              float* __restrict__ Mf)           // (2,512,512)
{
    const int d  = blockIdx.x * 256 + threadIdx.x;  // 0..511 (col of Mf)
    const int j0 = blockIdx.y * 4;                  // row of Mf
    const int l  = blockIdx.z;
    const float* wv = in_w + (size_t)l * 1536 * 512 + (size_t)1024 * 512;
    const float* ow = out_w + (size_t)l * 512 * 512;
    float a0 = 0.f, a1 = 0.f, a2 = 0.f, a3 = 0.f;
    for (int k = 0; k < 512; ++k) {
        float v = wv[(size_t)k * 512 + d];          // coalesced
        a0 = fmaf(ow[(j0 + 0) * 512 + k], v, a0);   // uniform scalar loads
        a1 = fmaf(ow[(j0 + 1) * 512 + k], v, a1);
        a2 = fmaf(ow[(j0 + 2) * 512 + k], v, a2);
        a3 = fmaf(ow[(j0 + 3) * 512 + k], v, a3);
    }
    float* o = Mf + (size_t)l * 512 * 512;
    o[(j0 + 0) * 512 + d] = a0;
    o[(j0 + 1) * 512 + d] = a1;
    o[(j0 + 2) * 512 + d] = a2;
    o[(j0 + 3) * 512 + d] = a3;
}

// beff_l = out_w_l @ bv_l + out_b_l
__global__ void fuse_b_kernel(const float* __restrict__ in_b,
                              const float* __restrict__ out_w,
                              const float* __restrict__ out_b,
                              float* __restrict__ beff)
{
    const int j = threadIdx.x;  // 0..511
    const int l = blockIdx.x;
    const float* bv = in_b + l * 1536 + 1024;
    const float* ow = out_w + (size_t)l * 512 * 512 + (size_t)j * 512;
    float acc = 0.f;
    for (int k = 0; k < 512; ++k) acc = fmaf(ow[k], bv[k], acc);
    beff[l * 512 + j] = acc + out_b[l * 512 + j];
}

// At(C,R) = A(R,C)^T — tiny matrices only (<=0.5 MB each)
__global__ void transpose_kernel(const float* __restrict__ A,
                                 float* __restrict__ At, int R, int C)
{
    int idx = blockIdx.x * 256 + threadIdx.x;
    if (idx >= R * C) return;
    int r = idx / C, c = idx - r * C;
    At[(size_t)c * R + r] = A[(size_t)r * C + c];
}

__device__ inline float wave_sum(float s)
{
#pragma unroll
    for (int o = 32; o > 0; o >>= 1) s += __shfl_xor(s, o);
    return s;
}

// ---------------------------------------------------------------------------
// attn_ln: out = LN(res + X @ M^T + bias)  with Wt = M^T pre-transposed
// (K-major: Wt[k][col], 512x512). Block = 256 thr = 4 waves, 16 rows.
// Thread cols: {4*tx..4*tx+3} and {256+4*tx..}.  All W loads coalesced float4.
// ---------------------------------------------------------------------------
__global__ __launch_bounds__(256) void attn_ln_kernel(
    const float* __restrict__ X, const float* __restrict__ Wt,
    const float* __restrict__ bias,
    const float* __restrict__ res, int res_stride,
    const float* __restrict__ lnw, const float* __restrict__ lnb,
    float* __restrict__ out)
{
    __shared__ float Xs[16][512];
    const int tid = threadIdx.x, tx = tid & 63, ty = tid >> 6;
    const int row0 = blockIdx.x * 16;

#pragma unroll
    for (int i = 0; i < 8; ++i) {
        int idx = tid + i * 256;
        int rr = idx >> 7, cc = idx & 127;
        *(float4*)&Xs[rr][cc * 4] =
            *(const float4*)&X[(size_t)(row0 + rr) * 512 + cc * 4];
    }
    __syncthreads();

    const float4* __restrict__ Wt4 = (const float4*)Wt;  // 128 float4 per k-row
    float4 acc[4][2];
#pragma unroll
    for (int r = 0; r < 4; ++r)
#pragma unroll
        for (int j = 0; j < 2; ++j) acc[r][j] = make_float4(0.f, 0.f, 0.f, 0.f);

    for (int k0 = 0; k0 < 512; k0 += 4) {
        float4 a[4];
#pragma unroll
        for (int r = 0; r < 4; ++r)
            a[r] = *(const float4*)&Xs[ty * 4 + r][k0];   // wave-broadcast
#pragma unroll
        for (int kk = 0; kk < 4; ++kk) {
            float4 w0 = Wt4[(size_t)(k0 + kk) * 128 + tx];
            float4 w1 = Wt4[(size_t)(k0 + kk) * 128 + 64 + tx];
#pragma unroll
            for (int r = 0; r < 4; ++r) {
                float av = (kk == 0) ? a[r].x : (kk == 1) ? a[r].y
                         : (kk == 2) ? a[r].z : a[r].w;
                acc[r][0].x = fmaf(av, w0.x, acc[r][0].x);
                acc[r][0].y = fmaf(av, w0.y, acc[r][0].y);
                acc[r][0].z = fmaf(av, w0.z, acc[r][0].z);
                acc[r][0].w = fmaf(av, w0.w, acc[r][0].w);
                acc[r][1].x = fmaf(av, w1.x, acc[r][1].x);
                acc[r][1].y = fmaf(av, w1.y, acc[r][1].y);
                acc[r][1].z = fmaf(av, w1.z, acc[r][1].z);
                acc[r][1].w = fmaf(av, w1.w, acc[r][1].w);
            }
        }
    }

    const int cb = tx * 4;
    float4 b0 = *(const float4*)&bias[cb];
    float4 b1 = *(const float4*)&bias[256 + cb];
    float4 g0 = *(const float4*)&lnw[cb];
    float4 g1 = *(const float4*)&lnw[256 + cb];
    float4 e0 = *(const float4*)&lnb[cb];
    float4 e1 = *(const float4*)&lnb[256 + cb];

#pragma unroll
    for (int r = 0; r < 4; ++r) {
        const int row = row0 + ty * 4 + r;
        float4 r0 = *(const float4*)&res[(size_t)row * res_stride + cb];
        float4 r1 = *(const float4*)&res[(size_t)row * res_stride + 256 + cb];
        float4 v0, v1;
        v0.x = acc[r][0].x + b0.x + r0.x;  v0.y = acc[r][0].y + b0.y + r0.y;
        v0.z = acc[r][0].z + b0.z + r0.z;  v0.w = acc[r][0].w + b0.w + r0.w;
        v1.x = acc[r][1].x + b1.x + r1.x;  v1.y = acc[r][1].y + b1.y + r1.y;
        v1.z = acc[r][1].z + b1.z + r1.z;  v1.w = acc[r][1].w + b1.w + r1.w;
        float s = v0.x + v0.y + v0.z + v0.w + v1.x + v1.y + v1.z + v1.w;
        s = wave_sum(s);
        const float mu = s * (1.0f / 512.0f);
        float q;
        float vv = 0.f;
        q = v0.x - mu; vv = fmaf(q, q, vv);  q = v0.y - mu; vv = fmaf(q, q, vv);
        q = v0.z - mu; vv = fmaf(q, q, vv);  q = v0.w - mu; vv = fmaf(q, q, vv);
        q = v1.x - mu; vv = fmaf(q, q, vv);  q = v1.y - mu; vv = fmaf(q, q, vv);
        q = v1.z - mu; vv = fmaf(q, q, vv);  q = v1.w - mu; vv = fmaf(q, q, vv);
        vv = wave_sum(vv);
        const float rstd = rsqrtf(vv * (1.0f / 512.0f) + 1e-5f);
        float4 o0, o1;
        o0.x = (v0.x - mu) * rstd * g0.x + e0.x;
        o0.y = (v0.y - mu) * rstd * g0.y + e0.y;
        o0.z = (v0.z - mu) * rstd * g0.z + e0.z;
        o0.w = (v0.w - mu) * rstd * g0.w + e0.w;
        o1.x = (v1.x - mu) * rstd * g1.x + e1.x;
        o1.y = (v1.y - mu) * rstd * g1.y + e1.y;
        o1.z = (v1.z - mu) * rstd * g1.z + e1.z;
        o1.w = (v1.w - mu) * rstd * g1.w + e1.w;
        *(float4*)&out[(size_t)row * 512 + cb] = o0;
        *(float4*)&out[(size_t)row * 512 + 256 + cb] = o1;
    }
}

// ---------------------------------------------------------------------------
// ffn_ln: out = LN(X + relu(X@w1^T+b1)@w2^T + b2) — h staged in LDS,
// residual read from the staged X tile (no extra global traffic).
// W1t: (512,256) K-major; W2t: (256,512) K-major.
// ---------------------------------------------------------------------------
__global__ __launch_bounds__(256) void ffn_ln_kernel(
    const float* __restrict__ X,
    const float* __restrict__ W1t, const float* __restrict__ b1,
    const float* __restrict__ W2t, const float* __restrict__ b2,
    const float* __restrict__ lnw, const float* __restrict__ lnb,
    float* __restrict__ out)
{
    __shared__ float Xs[16][512];
    __shared__ float Hs[16][256];
    const int tid = threadIdx.x, tx = tid & 63, ty = tid >> 6;
    const int row0 = blockIdx.x * 16;

#pragma unroll
    for (int i = 0; i < 8; ++i) {
        int idx = tid + i * 256;
        int rr = idx >> 7, cc = idx & 127;
        *(float4*)&Xs[rr][cc * 4] =
            *(const float4*)&X[(size_t)(row0 + rr) * 512 + cc * 4];
    }
    __syncthreads();

    // GEMM1: (16x512) @ (512x256) -> h
    const float4* __restrict__ W1t4 = (const float4*)W1t;  // 64 f4 per k-row
    float4 acc1[4];
#pragma unroll
    for (int r = 0; r < 4; ++r) acc1[r] = make_float4(0.f, 0.f, 0.f, 0.f);
    for (int k0 = 0; k0 < 512; k0 += 4) {
        float4 a[4];
#pragma unroll
        for (int r = 0; r < 4; ++r)
            a[r] = *(const float4*)&Xs[ty * 4 + r][k0];
#pragma unroll
        for (int kk = 0; kk < 4; ++kk) {
            float4 w = W1t4[(size_t)(k0 + kk) * 64 + tx];
#pragma unroll
            for (int r = 0; r < 4; ++r) {
                float av = (kk == 0) ? a[r].x : (kk == 1) ? a[r].y
                         : (kk == 2) ? a[r].z : a[r].w;
                acc1[r].x = fmaf(av, w.x, acc1[r].x);
                acc1[r].y = fmaf(av, w.y, acc1[r].y);
                acc1[r].z = fmaf(av, w.z, acc1[r].z);
                acc1[r].w = fmaf(av, w.w, acc1[r].w);
            }
        }
    }
    {
        float4 bb = *(const float4*)&b1[tx * 4];
#pragma unroll
        for (int r = 0; r < 4; ++r) {
            float4 h;
            h.x = fmaxf(acc1[r].x + bb.x, 0.f);
            h.y = fmaxf(acc1[r].y + bb.y, 0.f);
            h.z = fmaxf(acc1[r].z + bb.z, 0.f);
            h.w = fmaxf(acc1[r].w + bb.w, 0.f);
            *(float4*)&Hs[ty * 4 + r][tx * 4] = h;
        }
    }
    __syncthreads();

    // GEMM2: (16x256) @ (256x512)
    const float4* __restrict__ W2t4 = (const float4*)W2t;  // 128 f4 per k-row
    float4 acc[4][2];
#pragma unroll
    for (int r = 0; r < 4; ++r)
#pragma unroll
        for (int j = 0; j < 2; ++j) acc[r][j] = make_float4(0.f, 0.f, 0.f, 0.f);
    for (int k0 = 0; k0 < 256; k0 += 4) {
        float4 a[4];
#pragma unroll
        for (int r = 0; r < 4; ++r)
            a[r] = *(const float4*)&Hs[ty * 4 + r][k0];
#pragma unroll
        for (int kk = 0; kk < 4; ++kk) {
            float4 w0 = W2t4[(size_t)(k0 + kk) * 128 + tx];
            float4 w1 = W2t4[(size_t)(k0 + kk) * 128 + 64 + tx];
#pragma unroll
            for (int r = 0; r < 4; ++r) {
                float av = (kk == 0) ? a[r].x : (kk == 1) ? a[r].y
                         : (kk == 2) ? a[r].z : a[r].w;
                acc[r][0].x = fmaf(av, w0.x, acc[r][0].x);
                acc[r][0].y = fmaf(av, w0.y, acc[r][0].y);
                acc[r][0].z = fmaf(av, w0.z, acc[r][0].z);
                acc[r][0].w = fmaf(av, w0.w, acc[r][0].w);
                acc[r][1].x = fmaf(av, w1.x, acc[r][1].x);
                acc[r][1].y = fmaf(av, w1.y, acc[r][1].y);
                acc[r][1].z = fmaf(av, w1.z, acc[r][1].z);
                acc[r][1].w = fmaf(av, w1.w, acc[r][1].w);
            }
        }
    }

    const int cb = tx * 4;
    float4 b20 = *(const float4*)&b2[cb];
    float4 b21 = *(const float4*)&b2[256 + cb];
    float4 g0 = *(const float4*)&lnw[cb];
    float4 g1 = *(const float4*)&lnw[256 + cb];
    float4 e0 = *(const float4*)&lnb[cb];
    float4 e1 = *(const float4*)&lnb[256 + cb];

#pragma unroll
    for (int r = 0; r < 4; ++r) {
        const int row = row0 + ty * 4 + r;
        float4 r0 = *(const float4*)&Xs[ty * 4 + r][cb];        // residual = X
        float4 r1 = *(const float4*)&Xs[ty * 4 + r][256 + cb];
        float4 v0, v1;
        v0.x = acc[r][0].x + b20.x + r0.x;  v0.y = acc[r][0].y + b20.y + r0.y;
        v0.z = acc[r][0].z + b20.z + r0.z;  v0.w = acc[r][0].w + b20.w + r0.w;
        v1.x = acc[r][1].x + b21.x + r1.x;  v1.y = acc[r][1].y + b21.y + r1.y;
        v1.z = acc[r][1].z + b21.z + r1.z;  v1.w = acc[r][1].w + b21.w + r1.w;
        float s = v0.x + v0.y + v0.z + v0.w + v1.x + v1.y + v1.z + v1.w;
        s = wave_sum(s);
        const float mu = s * (1.0f / 512.0f);
        float q, vv = 0.f;
        q = v0.x - mu; vv = fmaf(q, q, vv);  q = v0.y - mu; vv = fmaf(q, q, vv);
        q = v0.z - mu; vv = fmaf(q, q, vv);  q = v0.w - mu; vv = fmaf(q, q, vv);
        q = v1.x - mu; vv = fmaf(q, q, vv);  q = v1.y - mu; vv = fmaf(q, q, vv);
        q = v1.z - mu; vv = fmaf(q, q, vv);  q = v1.w - mu; vv = fmaf(q, q, vv);
        vv = wave_sum(vv);
        const float rstd = rsqrtf(vv * (1.0f / 512.0f) + 1e-5f);
        float4 o0, o1;
        o0.x = (v0.x - mu) * rstd * g0.x + e0.x;
        o0.y = (v0.y - mu) * rstd * g0.y + e0.y;
        o0.z = (v0.z - mu) * rstd * g0.z + e0.z;
        o0.w = (v0.w - mu) * rstd * g0.w + e0.w;
        o1.x = (v1.x - mu) * rstd * g1.x + e1.x;
        o1.y = (v1.y - mu) * rstd * g1.y + e1.y;
        o1.z = (v1.z - mu) * rstd * g1.z + e1.z;
        o1.w = (v1.w - mu) * rstd * g1.w + e1.w;
        *(float4*)&out[(size_t)row * 512 + cb] = o0;
        *(float4*)&out[(size_t)row * 512 + 256 + cb] = o1;
    }
}

// ---------------------------------------------------------------------------
// head: out = sigmoid(relu([q,c]@head_w1^T + b1) @ head_w2^T + b2)
// H1t: (1024,256) K-major. Hidden stays in registers; per-row dot + wave reduce.
// ---------------------------------------------------------------------------
__global__ __launch_bounds__(256) void head_kernel(
    const float* __restrict__ Xq, const float* __restrict__ Xc,
    const float* __restrict__ H1t, const float* __restrict__ b1,
    const float* __restrict__ w2, const float* __restrict__ b2,
    float* __restrict__ out)
{
    __shared__ float Xs[16][512];
    const int tid = threadIdx.x, tx = tid & 63, ty = tid >> 6;
    const int row0 = blockIdx.x * 16;

    const float4* __restrict__ H1t4 = (const float4*)H1t;  // 64 f4 per k-row
    float4 acc1[4];
#pragma unroll
    for (int r = 0; r < 4; ++r) acc1[r] = make_float4(0.f, 0.f, 0.f, 0.f);

    for (int pass = 0; pass < 2; ++pass) {
        const float* X = pass ? Xc : Xq;
        __syncthreads();
#pragma unroll
        for (int i = 0; i < 8; ++i) {
            int idx = tid + i * 256;
            int rr = idx >> 7, cc = idx & 127;
            *(float4*)&Xs[rr][cc * 4] =
                *(const float4*)&X[(size_t)(row0 + rr) * 512 + cc * 4];
        }
        __syncthreads();
        const int kbase = pass * 512;
        for (int k0 = 0; k0 < 512; k0 += 4) {
            float4 a[4];
#pragma unroll
            for (int r = 0; r < 4; ++r)
                a[r] = *(const float4*)&Xs[ty * 4 + r][k0];
#pragma unroll
            for (int kk = 0; kk < 4; ++kk) {
                float4 w = H1t4[(size_t)(kbase + k0 + kk) * 64 + tx];
#pragma unroll
                for (int r = 0; r < 4; ++r) {
                    float av = (kk == 0) ? a[r].x : (kk == 1) ? a[r].y
                             : (kk == 2) ? a[r].z : a[r].w;
                    acc1[r].x = fmaf(av, w.x, acc1[r].x);
                    acc1[r].y = fmaf(av, w.y, acc1[r].y);
                    acc1[r].z = fmaf(av, w.z, acc1[r].z);
                    acc1[r].w = fmaf(av, w.w, acc1[r].w);
                }
            }
        }
    }

    float4 bb = *(const float4*)&b1[tx * 4];
    float4 w24 = *(const float4*)&w2[tx * 4];
    const float bias2 = b2[0];
#pragma unroll
    for (int r = 0; r < 4; ++r) {
        float hx = fmaxf(acc1[r].x + bb.x, 0.f);
        float hy = fmaxf(acc1[r].y + bb.y, 0.f);
        float hz = fmaxf(acc1[r].z + bb.z, 0.f);
        float hw = fmaxf(acc1[r].w + bb.w, 0.f);
        float s = hx * w24.x + hy * w24.y + hz * w24.z + hw * w24.w;
        s = wave_sum(s);
        if (tx == 0)
            out[row0 + ty * 4 + r] = 1.f / (1.f + expf(-(s + bias2)));
    }
}

// ---------------------------------------------------------------------------
extern "C" void kernel_launch(void* const* d_in, const int* in_sizes, int n_in,
                              void* d_out, int out_size, void* d_ws, size_t ws_size,
                              hipStream_t stream)
{
    const float* query      = (const float*)d_in[0];
    const float* cand       = (const float*)d_in[1];
    const float* attn_in_w  = (const float*)d_in[2];
    const float* attn_in_b  = (const float*)d_in[3];
    const float* attn_out_w = (const float*)d_in[4];
    const float* attn_out_b = (const float*)d_in[5];
    const float* ln_w       = (const float*)d_in[6];
    const float* ln_b       = (const float*)d_in[7];
    const float* ffn_w1     = (const float*)d_in[8];
    const float* ffn_b1     = (const float*)d_in[9];
    const float* ffn_w2     = (const float*)d_in[10];
    const float* ffn_b2     = (const float*)d_in[11];
    const float* head_w1    = (const float*)d_in[12];
    const float* head_b1    = (const float*)d_in[13];
    const float* head_w2    = (const float*)d_in[14];
    const float* head_b2    = (const float*)d_in[15];
    float* out = (float*)d_out;

    float* ws = (float*)d_ws;
    size_t o = 0;
    float* q_ws = ws + o;  o += (size_t)NROWS * 512;
    float* c_ws = ws + o;  o += (size_t)NROWS * 512;
    float* Mf   = ws + o;  o += 2 * 512 * 512;   // fused attn weight (row-major)
    float* Mft  = ws + o;  o += 2 * 512 * 512;   // K-major
    float* w1t  = ws + o;  o += 2 * 512 * 256;
    float* w2t  = ws + o;  o += 2 * 256 * 512;
    float* h1t  = ws + o;  o += 1024 * 256;
    float* beff = ws + o;  o += 1024;

    // ---- prep (tiny) ----
    fuse_w_kernel<<<dim3(2, 128, 2), 256, 0, stream>>>(attn_in_w, attn_out_w, Mf);
    fuse_b_kernel<<<2, 512, 0, stream>>>(attn_in_b, attn_out_w, attn_out_b, beff);
    for (int l = 0; l < 2; ++l) {
        transpose_kernel<<<1024, 256, 0, stream>>>(Mf + (size_t)l * 512 * 512,
                                                   Mft + (size_t)l * 512 * 512, 512, 512);
        transpose_kernel<<<512, 256, 0, stream>>>(ffn_w1 + (size_t)l * 256 * 512,
                                                  w1t + (size_t)l * 512 * 256, 256, 512);
        transpose_kernel<<<512, 256, 0, stream>>>(ffn_w2 + (size_t)l * 512 * 256,
                                                  w2t + (size_t)l * 256 * 512, 512, 256);
    }
    transpose_kernel<<<1024, 256, 0, stream>>>(head_w1, h1t, 256, 1024);

    const int NB = NROWS / 16;  // 8192 blocks
    for (int l = 0; l < 2; ++l) {
        const float* Ml = Mft + (size_t)l * 512 * 512;
        const float* bl = beff + l * 512;
        const float* lw = ln_w + l * 512;
        const float* lb = ln_b + l * 512;
        const float* W1 = w1t + (size_t)l * 512 * 256;
        const float* B1 = ffn_b1 + l * 256;
        const float* W2 = w2t + (size_t)l * 256 * 512;
        const float* B2 = ffn_b2 + l * 512;

        // q = LN(res_q + c_in @ M^T + beff)
        if (l == 0)
            attn_ln_kernel<<<NB, 256, 0, stream>>>(cand, Ml, bl, query, 0, lw, lb, q_ws);
        else
            attn_ln_kernel<<<NB, 256, 0, stream>>>(c_ws, Ml, bl, q_ws, 512, lw, lb, q_ws);
        // q = LN(q + ffn(q))
        ffn_ln_kernel<<<NB, 256, 0, stream>>>(q_ws, W1, B1, W2, B2, lw, lb, q_ws);
        // c = LN(c_in + q @ M^T + beff)
        const float* c_in = (l == 0) ? cand : c_ws;
        attn_ln_kernel<<<NB, 256, 0, stream>>>(q_ws, Ml, bl, c_in, 512, lw, lb, c_ws);
        // c = LN(c + ffn(c))
        ffn_ln_kernel<<<NB, 256, 0, stream>>>(c_ws, W1, B1, W2, B2, lw, lb, c_ws);
    }
    // head
    head_kernel<<<NB, 256, 0, stream>>>(q_ws, c_ws, h1t, head_b1, head_w2, head_b2, out);
}

// Round 4
// 2553.554 us; speedup vs baseline: 4.1499x; 4.1499x over previous
//
#include <hip/hip_runtime.h>
#include <hip/hip_bf16.h>
#include <math.h>

#define NROWS 131072

typedef __attribute__((ext_vector_type(8))) _Float16 half8;
typedef __attribute__((ext_vector_type(4))) _Float16 half4;
typedef __attribute__((ext_vector_type(4))) float   f32x4;

#define MFMA16(a, b, c) __builtin_amdgcn_mfma_f32_16x16x32_f16((a), (b), (c), 0, 0, 0)

// ---------------------------------------------------------------------------
// Prep: Mf[l] = out_w[l] @ wv[l]  (fp32). softmax over size-1 axis == 1, so
// mha(x_q, x_kv) = x_kv @ (out_w@wv)^T + (out_w@bv + out_b).
// ---------------------------------------------------------------------------
__global__ void fuse_w_kernel(const float* __restrict__ in_w,   // (2,1536,512)
                              const float* __restrict__ out_w,  // (2,512,512)
                              float* __restrict__ Mf)           // (2,512,512)
{
    const int d  = blockIdx.x * 256 + threadIdx.x;  // k index
    const int j0 = blockIdx.y * 4;                  // output-col index
    const int l  = blockIdx.z;
    const float* wv = in_w + (size_t)l * 1536 * 512 + (size_t)1024 * 512;
    const float* ow = out_w + (size_t)l * 512 * 512;
    float a0 = 0.f, a1 = 0.f, a2 = 0.f, a3 = 0.f;
    for (int k = 0; k < 512; ++k) {
        float v = wv[(size_t)k * 512 + d];
        a0 = fmaf(ow[(j0 + 0) * 512 + k], v, a0);
        a1 = fmaf(ow[(j0 + 1) * 512 + k], v, a1);
        a2 = fmaf(ow[(j0 + 2) * 512 + k], v, a2);
        a3 = fmaf(ow[(j0 + 3) * 512 + k], v, a3);
    }
    float* o = Mf + (size_t)l * 512 * 512;
    o[(j0 + 0) * 512 + d] = a0;
    o[(j0 + 1) * 512 + d] = a1;
    o[(j0 + 2) * 512 + d] = a2;
    o[(j0 + 3) * 512 + d] = a3;
}

__global__ void fuse_b_kernel(const float* __restrict__ in_b,
                              const float* __restrict__ out_w,
                              const float* __restrict__ out_b,
                              float* __restrict__ beff)
{
    const int j = threadIdx.x;  // 0..511
    const int l = blockIdx.x;
    const float* bv = in_b + l * 1536 + 1024;
    const float* ow = out_w + (size_t)l * 512 * 512 + (size_t)j * 512;
    float acc = 0.f;
    for (int k = 0; k < 512; ++k) acc = fmaf(ow[k], bv[k], acc);
    beff[l * 512 + j] = acc + out_b[l * 512 + j];
}

// fp32 -> fp16, vectorized x4
__global__ void f2h_kernel(const float4* __restrict__ src,
                           half4* __restrict__ dst, int n4)
{
    int i = blockIdx.x * 256 + threadIdx.x;
    if (i >= n4) return;
    float4 v = src[i];
    half4 h;
    h[0] = (_Float16)v.x; h[1] = (_Float16)v.y;
    h[2] = (_Float16)v.z; h[3] = (_Float16)v.w;
    dst[i] = h;
}

// ---------------------------------------------------------------------------
// attn+LN: out = LN(res + X @ M^T + bias), all activations f16, acc fp32.
// Block: 256 thr = 4 waves; 64 rows; wave w owns cols [w*128, w*128+128).
// A-frag: lane reads X[row0+rg*16+(l&15)][k0+(l>>4)*8 ..+7]  (16B)
// B-frag: lane reads W[c0+cg*16+(l&15)][k0+(l>>4)*8 ..+7]    (16B, W=(M,K) row-major)
// C/D: col=lane&15, row=(lane>>4)*4+reg  [m89-verified]
// ---------------------------------------------------------------------------
__global__ __launch_bounds__(256, 2) void attn_mfma_kernel(
    const _Float16* __restrict__ X,
    const _Float16* __restrict__ W,
    const float* __restrict__ bias,
    const _Float16* __restrict__ res, const int res_bcast,
    const float* __restrict__ lnw, const float* __restrict__ lnb,
    _Float16* __restrict__ out)
{
    __shared__ float sS[4][64];
    __shared__ float sQ[4][64];
    const int tid  = threadIdx.x;
    const int lane = tid & 63;
    const int wv   = tid >> 6;
    const int l15  = lane & 15;
    const int lq   = lane >> 4;
    const int row0 = blockIdx.x * 64;
    const int c0   = wv * 128;

    f32x4 acc[4][8];
#pragma unroll
    for (int rg = 0; rg < 4; ++rg)
#pragma unroll
        for (int cg = 0; cg < 8; ++cg) acc[rg][cg] = f32x4{0.f, 0.f, 0.f, 0.f};

    const _Float16* Xa = X + (size_t)(row0 + l15) * 512 + lq * 8;
    const _Float16* Wb = W + (size_t)(c0 + l15) * 512 + lq * 8;

#pragma unroll 2
    for (int k0 = 0; k0 < 512; k0 += 32) {
        half8 a[4];
#pragma unroll
        for (int rg = 0; rg < 4; ++rg)
            a[rg] = *(const half8*)(Xa + (size_t)rg * 16 * 512 + k0);
#pragma unroll
        for (int cg = 0; cg < 8; ++cg) {
            half8 b = *(const half8*)(Wb + (size_t)cg * 16 * 512 + k0);
#pragma unroll
            for (int rg = 0; rg < 4; ++rg)
                acc[rg][cg] = MFMA16(a[rg], b, acc[rg][cg]);
        }
    }

    // bias + residual
#pragma unroll
    for (int cg = 0; cg < 8; ++cg) {
        const int col = c0 + cg * 16 + l15;
        const float bi = bias[col];
#pragma unroll
        for (int rg = 0; rg < 4; ++rg)
#pragma unroll
            for (int r = 0; r < 4; ++r) {
                const int row = row0 + rg * 16 + lq * 4 + r;
                const float rv = (float)(res_bcast ? res[col]
                                                   : res[(size_t)row * 512 + col]);
                acc[rg][cg][r] += bi + rv;
            }
    }

    // LN pass 1: row sums (cross-lane within 16-group, then cross-wave via LDS)
    float s[4][4];
#pragma unroll
    for (int rg = 0; rg < 4; ++rg)
#pragma unroll
        for (int r = 0; r < 4; ++r) {
            float t = 0.f;
#pragma unroll
            for (int cg = 0; cg < 8; ++cg) t += acc[rg][cg][r];
            s[rg][r] = t;
        }
#pragma unroll
    for (int o = 1; o <= 8; o <<= 1)
#pragma unroll
        for (int rg = 0; rg < 4; ++rg)
#pragma unroll
            for (int r = 0; r < 4; ++r) s[rg][r] += __shfl_xor(s[rg][r], o);
    if (l15 == 0)
#pragma unroll
        for (int rg = 0; rg < 4; ++rg)
#pragma unroll
            for (int r = 0; r < 4; ++r) sS[wv][rg * 16 + lq * 4 + r] = s[rg][r];
    __syncthreads();
    float mu[4][4];
#pragma unroll
    for (int rg = 0; rg < 4; ++rg)
#pragma unroll
        for (int r = 0; r < 4; ++r) {
            const int rr = rg * 16 + lq * 4 + r;
            mu[rg][r] = (sS[0][rr] + sS[1][rr] + sS[2][rr] + sS[3][rr]) *
                        (1.0f / 512.0f);
        }
    // LN pass 2: variance
#pragma unroll
    for (int rg = 0; rg < 4; ++rg)
#pragma unroll
        for (int r = 0; r < 4; ++r) {
            float t = 0.f;
#pragma unroll
            for (int cg = 0; cg < 8; ++cg) {
                const float d = acc[rg][cg][r] - mu[rg][r];
                t = fmaf(d, d, t);
            }
            s[rg][r] = t;
        }
#pragma unroll
    for (int o = 1; o <= 8; o <<= 1)
#pragma unroll
        for (int rg = 0; rg < 4; ++rg)
#pragma unroll
            for (int r = 0; r < 4; ++r) s[rg][r] += __shfl_xor(s[rg][r], o);
    if (l15 == 0)
#pragma unroll
        for (int rg = 0; rg < 4; ++rg)
#pragma unroll
            for (int r = 0; r < 4; ++r) sQ[wv][rg * 16 + lq * 4 + r] = s[rg][r];
    __syncthreads();
    float rs[4][4];
#pragma unroll
    for (int rg = 0; rg < 4; ++rg)
#pragma unroll
        for (int r = 0; r < 4; ++r) {
            const int rr = rg * 16 + lq * 4 + r;
            rs[rg][r] = rsqrtf((sQ[0][rr] + sQ[1][rr] + sQ[2][rr] + sQ[3][rr]) *
                                   (1.0f / 512.0f) + 1e-5f);
        }
    // normalize + store f16
#pragma unroll
    for (int cg = 0; cg < 8; ++cg) {
        const int col = c0 + cg * 16 + l15;
        const float g = lnw[col], e = lnb[col];
#pragma unroll
        for (int rg = 0; rg < 4; ++rg)
#pragma unroll
            for (int r = 0; r < 4; ++r) {
                const int row = row0 + rg * 16 + lq * 4 + r;
                out[(size_t)row * 512 + col] =
                    (_Float16)((acc[rg][cg][r] - mu[rg][r]) * rs[rg][r] * g + e);
            }
    }
}

// ---------------------------------------------------------------------------
// FFN pair fused: out = LN(X + relu(X@W1^T+b1)@W2^T + b2)
// GEMM1: wave owns 64 cols of 256; h -> padded LDS. GEMM2: A from LDS.
// ---------------------------------------------------------------------------
__global__ __launch_bounds__(256, 2) void ffn_mfma_kernel(
    const _Float16* __restrict__ X,
    const _Float16* __restrict__ W1, const float* __restrict__ b1,
    const _Float16* __restrict__ W2, const float* __restrict__ b2,
    const float* __restrict__ lnw, const float* __restrict__ lnb,
    _Float16* __restrict__ out)
{
    __shared__ _Float16 Hs[64][264];   // +8 pad keeps 16B align, kills conflicts
    __shared__ float sS[4][64];
    __shared__ float sQ[4][64];
    const int tid  = threadIdx.x;
    const int lane = tid & 63;
    const int wv   = tid >> 6;
    const int l15  = lane & 15;
    const int lq   = lane >> 4;
    const int row0 = blockIdx.x * 64;

    // ---- GEMM1: (64x512)@(512->256), wave cols [wv*64, wv*64+64) ----
    {
        const int c1 = wv * 64;
        f32x4 acc1[4][4];
#pragma unroll
        for (int rg = 0; rg < 4; ++rg)
#pragma unroll
            for (int cg = 0; cg < 4; ++cg) acc1[rg][cg] = f32x4{0.f, 0.f, 0.f, 0.f};
        const _Float16* Xa = X + (size_t)(row0 + l15) * 512 + lq * 8;
        const _Float16* Wb = W1 + (size_t)(c1 + l15) * 512 + lq * 8;
#pragma unroll 2
        for (int k0 = 0; k0 < 512; k0 += 32) {
            half8 a[4];
#pragma unroll
            for (int rg = 0; rg < 4; ++rg)
                a[rg] = *(const half8*)(Xa + (size_t)rg * 16 * 512 + k0);
#pragma unroll
            for (int cg = 0; cg < 4; ++cg) {
                half8 b = *(const half8*)(Wb + (size_t)cg * 16 * 512 + k0);
#pragma unroll
                for (int rg = 0; rg < 4; ++rg)
                    acc1[rg][cg] = MFMA16(a[rg], b, acc1[rg][cg]);
            }
        }
#pragma unroll
        for (int cg = 0; cg < 4; ++cg) {
            const int col = c1 + cg * 16 + l15;
            const float bi = b1[col];
#pragma unroll
            for (int rg = 0; rg < 4; ++rg)
#pragma unroll
                for (int r = 0; r < 4; ++r) {
                    const int rl = rg * 16 + lq * 4 + r;
                    Hs[rl][col] = (_Float16)fmaxf(acc1[rg][cg][r] + bi, 0.f);
                }
        }
    }
    __syncthreads();

    // ---- GEMM2: (64x256)@(256->512), wave cols [wv*128, ...) ----
    const int c0 = wv * 128;
    f32x4 acc[4][8];
#pragma unroll
    for (int rg = 0; rg < 4; ++rg)
#pragma unroll
        for (int cg = 0; cg < 8; ++cg) acc[rg][cg] = f32x4{0.f, 0.f, 0.f, 0.f};
    const _Float16* Wb2 = W2 + (size_t)(c0 + l15) * 256 + lq * 8;
#pragma unroll 2
    for (int k0 = 0; k0 < 256; k0 += 32) {
        half8 a[4];
#pragma unroll
        for (int rg = 0; rg < 4; ++rg)
            a[rg] = *(const half8*)(&Hs[rg * 16 + l15][k0 + lq * 8]);
#pragma unroll
        for (int cg = 0; cg < 8; ++cg) {
            half8 b = *(const half8*)(Wb2 + (size_t)cg * 16 * 256 + k0);
#pragma unroll
            for (int rg = 0; rg < 4; ++rg)
                acc[rg][cg] = MFMA16(a[rg], b, acc[rg][cg]);
        }
    }

    // epilogue: +b2 + residual X, LN, store
#pragma unroll
    for (int cg = 0; cg < 8; ++cg) {
        const int col = c0 + cg * 16 + l15;
        const float bi = b2[col];
#pragma unroll
        for (int rg = 0; rg < 4; ++rg)
#pragma unroll
            for (int r = 0; r < 4; ++r) {
                const int row = row0 + rg * 16 + lq * 4 + r;
                acc[rg][cg][r] += bi + (float)X[(size_t)row * 512 + col];
            }
    }
    float s[4][4];
#pragma unroll
    for (int rg = 0; rg < 4; ++rg)
#pragma unroll
        for (int r = 0; r < 4; ++r) {
            float t = 0.f;
#pragma unroll
            for (int cg = 0; cg < 8; ++cg) t += acc[rg][cg][r];
            s[rg][r] = t;
        }
#pragma unroll
    for (int o = 1; o <= 8; o <<= 1)
#pragma unroll
        for (int rg = 0; rg < 4; ++rg)
#pragma unroll
            for (int r = 0; r < 4; ++r) s[rg][r] += __shfl_xor(s[rg][r], o);
    if (l15 == 0)
#pragma unroll
        for (int rg = 0; rg < 4; ++rg)
#pragma unroll
            for (int r = 0; r < 4; ++r) sS[wv][rg * 16 + lq * 4 + r] = s[rg][r];
    __syncthreads();
    float mu[4][4];
#pragma unroll
    for (int rg = 0; rg < 4; ++rg)
#pragma unroll
        for (int r = 0; r < 4; ++r) {
            const int rr = rg * 16 + lq * 4 + r;
            mu[rg][r] = (sS[0][rr] + sS[1][rr] + sS[2][rr] + sS[3][rr]) *
                        (1.0f / 512.0f);
        }
#pragma unroll
    for (int rg = 0; rg < 4; ++rg)
#pragma unroll
        for (int r = 0; r < 4; ++r) {
            float t = 0.f;
#pragma unroll
            for (int cg = 0; cg < 8; ++cg) {
                const float d = acc[rg][cg][r] - mu[rg][r];
                t = fmaf(d, d, t);
            }
            s[rg][r] = t;
        }
#pragma unroll
    for (int o = 1; o <= 8; o <<= 1)
#pragma unroll
        for (int rg = 0; rg < 4; ++rg)
#pragma unroll
            for (int r = 0; r < 4; ++r) s[rg][r] += __shfl_xor(s[rg][r], o);
    if (l15 == 0)
#pragma unroll
        for (int rg = 0; rg < 4; ++rg)
#pragma unroll
            for (int r = 0; r < 4; ++r) sQ[wv][rg * 16 + lq * 4 + r] = s[rg][r];
    __syncthreads();
#pragma unroll
    for (int cg = 0; cg < 8; ++cg) {
        const int col = c0 + cg * 16 + l15;
        const float g = lnw[col], e = lnb[col];
#pragma unroll
        for (int rg = 0; rg < 4; ++rg)
#pragma unroll
            for (int r = 0; r < 4; ++r) {
                const int rr = rg * 16 + lq * 4 + r;
                const float rstd =
                    rsqrtf((sQ[0][rr] + sQ[1][rr] + sQ[2][rr] + sQ[3][rr]) *
                               (1.0f / 512.0f) + 1e-5f);
                out[(size_t)(row0 + rr) * 512 + col] =
                    (_Float16)((acc[rg][cg][r] - mu[rg][r]) * rstd * g + e);
            }
    }
}

// ---------------------------------------------------------------------------
// head fused: out = sigmoid(relu([q,c]@W^T + b1) @ w2 + b2)
// W = head_w1 f16 (256,1024). Wave owns 64 cols of 256; K=1024 via 2 passes.
// ---------------------------------------------------------------------------
__global__ __launch_bounds__(256, 2) void head_mfma_kernel(
    const _Float16* __restrict__ Xq, const _Float16* __restrict__ Xc,
    const _Float16* __restrict__ W,
    const float* __restrict__ b1, const float* __restrict__ w2,
    const float* __restrict__ b2, float* __restrict__ out)
{
    __shared__ float sS[4][64];
    const int tid  = threadIdx.x;
    const int lane = tid & 63;
    const int wv   = tid >> 6;
    const int l15  = lane & 15;
    const int lq   = lane >> 4;
    const int row0 = blockIdx.x * 64;
    const int c0   = wv * 64;

    f32x4 acc[4][4];
#pragma unroll
    for (int rg = 0; rg < 4; ++rg)
#pragma unroll
        for (int cg = 0; cg < 4; ++cg) acc[rg][cg] = f32x4{0.f, 0.f, 0.f, 0.f};

    for (int pass = 0; pass < 2; ++pass) {
        const _Float16* X = pass ? Xc : Xq;
        const _Float16* Xa = X + (size_t)(row0 + l15) * 512 + lq * 8;
        const _Float16* Wb = W + (size_t)(c0 + l15) * 1024 + pass * 512 + lq * 8;
#pragma unroll 2
        for (int k0 = 0; k0 < 512; k0 += 32) {
            half8 a[4];
#pragma unroll
            for (int rg = 0; rg < 4; ++rg)
                a[rg] = *(const half8*)(Xa + (size_t)rg * 16 * 512 + k0);
#pragma unroll
            for (int cg = 0; cg < 4; ++cg) {
                half8 b = *(const half8*)(Wb + (size_t)cg * 16 * 1024 + k0);
#pragma unroll
                for (int rg = 0; rg < 4; ++rg)
                    acc[rg][cg] = MFMA16(a[rg], b, acc[rg][cg]);
            }
        }
    }

    // relu(acc+b1) dot w2 per row
    float p[4][4];
#pragma unroll
    for (int rg = 0; rg < 4; ++rg)
#pragma unroll
        for (int r = 0; r < 4; ++r) p[rg][r] = 0.f;
#pragma unroll
    for (int cg = 0; cg < 4; ++cg) {
        const int col = c0 + cg * 16 + l15;
        const float bi = b1[col], wc = w2[col];
#pragma unroll
        for (int rg = 0; rg < 4; ++rg)
#pragma unroll
            for (int r = 0; r < 4; ++r)
                p[rg][r] = fmaf(fmaxf(acc[rg][cg][r] + bi, 0.f), wc, p[rg][r]);
    }
#pragma unroll
    for (int o = 1; o <= 8; o <<= 1)
#pragma unroll
        for (int rg = 0; rg < 4; ++rg)
#pragma unroll
            for (int r = 0; r < 4; ++r) p[rg][r] += __shfl_xor(p[rg][r], o);
    if (l15 == 0)
#pragma unroll
        for (int rg = 0; rg < 4; ++rg)
#pragma unroll
            for (int r = 0; r < 4; ++r) sS[wv][rg * 16 + lq * 4 + r] = p[rg][r];
    __syncthreads();
    if (tid < 64) {
        const float z = sS[0][tid] + sS[1][tid] + sS[2][tid] + sS[3][tid] + b2[0];
        out[row0 + tid] = 1.f / (1.f + expf(-z));
    }
}

// ---------------------------------------------------------------------------
extern "C" void kernel_launch(void* const* d_in, const int* in_sizes, int n_in,
                              void* d_out, int out_size, void* d_ws, size_t ws_size,
                              hipStream_t stream)
{
    const float* query      = (const float*)d_in[0];
    const float* cand       = (const float*)d_in[1];
    const float* attn_in_w  = (const float*)d_in[2];
    const float* attn_in_b  = (const float*)d_in[3];
    const float* attn_out_w = (const float*)d_in[4];
    const float* attn_out_b = (const float*)d_in[5];
    const float* ln_w       = (const float*)d_in[6];
    const float* ln_b       = (const float*)d_in[7];
    const float* ffn_w1     = (const float*)d_in[8];
    const float* ffn_b1     = (const float*)d_in[9];
    const float* ffn_w2     = (const float*)d_in[10];
    const float* ffn_b2     = (const float*)d_in[11];
    const float* head_w1    = (const float*)d_in[12];
    const float* head_b1    = (const float*)d_in[13];
    const float* head_w2    = (const float*)d_in[14];
    const float* head_b2    = (const float*)d_in[15];
    float* out = (float*)d_out;

    char* ws = (char*)d_ws;
    size_t o = 0;
    _Float16* qh   = (_Float16*)(ws + o); o += (size_t)NROWS * 512 * 2;
    _Float16* ch   = (_Float16*)(ws + o); o += (size_t)NROWS * 512 * 2;
    _Float16* c0h  = (_Float16*)(ws + o); o += (size_t)NROWS * 512 * 2;
    float*    Mf   = (float*)   (ws + o); o += (size_t)2 * 512 * 512 * 4;
    _Float16* Mfh  = (_Float16*)(ws + o); o += (size_t)2 * 512 * 512 * 2;
    _Float16* w1h  = (_Float16*)(ws + o); o += (size_t)2 * 256 * 512 * 2;
    _Float16* w2h  = (_Float16*)(ws + o); o += (size_t)2 * 512 * 256 * 2;
    _Float16* h1h  = (_Float16*)(ws + o); o += (size_t)256 * 1024 * 2;
    float*    beff = (float*)   (ws + o); o += 1024 * 4;
    _Float16* qrh  = (_Float16*)(ws + o); o += 512 * 2;

    // ---- prep ----
    fuse_w_kernel<<<dim3(2, 128, 2), 256, 0, stream>>>(attn_in_w, attn_out_w, Mf);
    fuse_b_kernel<<<2, 512, 0, stream>>>(attn_in_b, attn_out_w, attn_out_b, beff);
    f2h_kernel<<<512, 256, 0, stream>>>((const float4*)Mf, (half4*)Mfh, 131072);
    f2h_kernel<<<256, 256, 0, stream>>>((const float4*)ffn_w1, (half4*)w1h, 65536);
    f2h_kernel<<<256, 256, 0, stream>>>((const float4*)ffn_w2, (half4*)w2h, 65536);
    f2h_kernel<<<256, 256, 0, stream>>>((const float4*)head_w1, (half4*)h1h, 65536);
    f2h_kernel<<<1, 256, 0, stream>>>((const float4*)query, (half4*)qrh, 128);
    f2h_kernel<<<65536, 256, 0, stream>>>((const float4*)cand, (half4*)c0h, 16777216);

    const int NB = NROWS / 64;  // 2048 blocks
    for (int l = 0; l < 2; ++l) {
        const _Float16* Ml = Mfh + (size_t)l * 512 * 512;
        const float* bl = beff + l * 512;
        const float* lw = ln_w + l * 512;
        const float* lb = ln_b + l * 512;
        const _Float16* W1 = w1h + (size_t)l * 256 * 512;
        const float* B1 = ffn_b1 + l * 256;
        const _Float16* W2 = w2h + (size_t)l * 512 * 256;
        const float* B2 = ffn_b2 + l * 512;
        const _Float16* c_in = (l == 0) ? c0h : ch;

        // q = LN(res_q + c_in @ M^T + beff)
        if (l == 0)
            attn_mfma_kernel<<<NB, 256, 0, stream>>>(c_in, Ml, bl, qrh, 1, lw, lb, qh);
        else
            attn_mfma_kernel<<<NB, 256, 0, stream>>>(c_in, Ml, bl, qh, 0, lw, lb, qh);
        // q = LN(q + ffn(q))
        ffn_mfma_kernel<<<NB, 256, 0, stream>>>(qh, W1, B1, W2, B2, lw, lb, qh);
        // c = LN(c_in + q @ M^T + beff)
        attn_mfma_kernel<<<NB, 256, 0, stream>>>(qh, Ml, bl, c_in, 0, lw, lb, ch);
        // c = LN(c + ffn(c))
        ffn_mfma_kernel<<<NB, 256, 0, stream>>>(ch, W1, B1, W2, B2, lw, lb, ch);
    }
    head_mfma_kernel<<<NB, 256, 0, stream>>>(qh, ch, h1h, head_b1, head_w2,
                                             head_b2, out);
}